// Round 6
// baseline (1136.203 us; speedup 1.0000x reference)
//
#include <hip/hip_runtime.h>
#include <math.h>

#define T_TOK 32768
#define D_DIM 128
#define K_CODE 8192
#define BM 256              // tokens per window (argmin): 4 waves x 64
#define BN 64               // codes per block (argmin)
#define WW 4                // token windows per block (same staged A-tile)

typedef unsigned long long ull;
typedef _Float16 v8h __attribute__((ext_vector_type(8)));
typedef _Float16 v4h __attribute__((ext_vector_type(4)));
typedef float v16f __attribute__((ext_vector_type(16)));

#define SCALE 4096.0f        // 2^12: pushes f16 split residuals into normal range
#define DESCALE (1.0f / 4096.0f)
#define ACC_SCALE (-0x1p-23f)   // s' = cn - 2*dot (zn dropped: token-constant)

#define ZWIN_STRIDE 1048576   // 8 windows * 256 tok * 512 B: ww -> ww+1 byte stride

// Cpack layout (bytes): [cb=code/64][ (s*2+mt)*8+kc ][lane64][j8 f16]
// Zpack layout (bytes): [tb=token/32][ s ][ kc ][lane64][j8 f16]

// ---------------- prep: proj (blocks 0..2047) + prep_z (2048..3071) ---------
// Fused: the two producers are independent; separate dispatches serialized in
// stream order. One dispatch runs them concurrently across CUs.
__global__ __launch_bounds__(256) void prep_kernel(const float* __restrict__ E,
                                                   const float* __restrict__ W,
                                                   const float* __restrict__ b,
                                                   char* __restrict__ Cpack,
                                                   float* __restrict__ cn,
                                                   const float* __restrict__ Z,
                                                   char* __restrict__ Zpack,
                                                   ull* __restrict__ packed,
                                                   int* __restrict__ counts,
                                                   unsigned* __restrict__ done) {
    int tid = threadIdx.x;
    int lane = tid & 63;
    if (blockIdx.x < 2048) {
        // ---- proj: codebook row -> f16 split packs + cn (1 wave / row) ----
        int r = blockIdx.x * 4 + (tid >> 6);
        int l = lane;
        const float4* E4 = (const float4*)(E + (size_t)r * D_DIM);
        const float4* WA = (const float4*)(W + (size_t)l * D_DIM);
        const float4* WB = (const float4*)(W + (size_t)(l + 64) * D_DIM);

        float4 aA = make_float4(0.f, 0.f, 0.f, 0.f);
        float4 aB = make_float4(0.f, 0.f, 0.f, 0.f);
#pragma unroll
        for (int dd = 0; dd < 32; ++dd) {
            float4 e = E4[dd];
            float4 wa = WA[dd], wb = WB[dd];
            aA.x = fmaf(e.x, wa.x, aA.x);
            aA.y = fmaf(e.y, wa.y, aA.y);
            aA.z = fmaf(e.z, wa.z, aA.z);
            aA.w = fmaf(e.w, wa.w, aA.w);
            aB.x = fmaf(e.x, wb.x, aB.x);
            aB.y = fmaf(e.y, wb.y, aB.y);
            aB.z = fmaf(e.z, wb.z, aB.z);
            aB.w = fmaf(e.w, wb.w, aB.w);
        }
        float vA = ((aA.x + aA.y) + (aA.z + aA.w)) + b[l];
        float vB = ((aB.x + aB.y) + (aB.z + aB.w)) + b[l + 64];

        char* cp = Cpack + (size_t)(r >> 6) * 32768;
        int mt = (r >> 5) & 1, rs = r & 31;
        {   // d = l
            int kc = l >> 4, hf = (l >> 3) & 1, j = l & 7;
            float f = vA * SCALE;
            _Float16 h = (_Float16)f;
            _Float16 m = (_Float16)(f - (float)h);
            size_t off = (size_t)((mt * 8 + kc) * 1024 + (hf * 32 + rs) * 16 + j * 2);
            *(_Float16*)(cp + off) = h;
            *(_Float16*)(cp + off + 16384) = m;
        }
        {   // d = l + 64
            int d = l + 64;
            int kc = d >> 4, hf = (d >> 3) & 1, j = d & 7;
            float f = vB * SCALE;
            _Float16 h = (_Float16)f;
            _Float16 m = (_Float16)(f - (float)h);
            size_t off = (size_t)((mt * 8 + kc) * 1024 + (hf * 32 + rs) * 16 + j * 2);
            *(_Float16*)(cp + off) = h;
            *(_Float16*)(cp + off + 16384) = m;
        }

        float s = vA * vA + vB * vB;
#pragma unroll
        for (int off = 32; off > 0; off >>= 1) s += __shfl_down(s, off, 64);
        if (l == 0) cn[r] = s;
    } else {
        // ---- prep_z: z -> f16 split packs + fused inits ----
        int tb = blockIdx.x - 2048;   // 32-token group
        int w = tid >> 6;

        int g = tb * 256 + tid;
        if (g < T_TOK) packed[g] = ~0ull;
        if (g < K_CODE) counts[g] = 0;
        if (g == 0) *done = 0u;

        char* zp = Zpack + (size_t)tb * 16384;
#pragma unroll
        for (int kq = 0; kq < 2; ++kq) {
            int kc = 2 * w + kq;
            const float* src = Z + (size_t)(tb * 32 + (lane & 31)) * D_DIM
                                 + kc * 16 + (lane >> 5) * 8;
            float4 a = *(const float4*)(src);
            float4 c = *(const float4*)(src + 4);
            float vals[8] = {a.x, a.y, a.z, a.w, c.x, c.y, c.z, c.w};
            v8h h, m;
#pragma unroll
            for (int j = 0; j < 8; ++j) {
                float f = vals[j] * SCALE;
                _Float16 hh = (_Float16)f;
                h[j] = hh;
                m[j] = (_Float16)(f - (float)hh);
            }
            *(v8h*)(zp + (size_t)(kc * 1024 + lane * 16)) = h;
            *(v8h*)(zp + (size_t)(8192 + kc * 1024 + lane * 16)) = m;
        }
    }
}

// ---------------- MFMA argmin: one A-stage amortized over 4 windows ---------
// R15 post-mortem: R5's +22% occupancy gave Δt=0 -> not wave-starved. Per
// block, matrix work is only 3072 cyc/wave (96 MFMA x 32 cyc/SIMD) while the
// stage+barrier head (~1k cyc) + epilogue tail repeat 16x/CU, and co-resident
// blocks convoy (identical durations -> heads coincide -> pipe drains). Fix:
// WW=4 windows per block reuse ONE staged A-tile: head paid 4x/CU not 16x,
// per-wave matrix per stage 4x (12288 cyc), mid-block epilogues barrier-free
// (overlap other waves' MFMA). pb handoff across windows = R2's verified
// (kc<6 ? cur : next) trick; refills skipped at ww=WW-1 (no OOB). Registers,
// LDS, inner-loop arithmetic, swizzle, tie-breaks identical to R5.
__global__ __launch_bounds__(256, 4) void argmin_kernel(const char* __restrict__ Zpack,
                                                        const char* __restrict__ Cpack,
                                                        const float* __restrict__ cn,
                                                        ull* __restrict__ packed) {
    __shared__ __align__(16) char lds[33024];   // 32768 A-pack + 256 cn

    int tid = threadIdx.x;
    int lane = tid & 63;
    int w = tid >> 6;                  // 0..3
    int half_id = lane >> 5;

    // bid bits: [2:0]=xcd, [9:3]=cb, [11:10]=wq. XCD k handles windows
    // k+32*wq+8*ww -> during each wq-phase an XCD's blocks co-sweep 4 windows
    // (512 KB Zpack, L2-hot) across all 128 cbs; Cpack staged once per block.
    int bid = blockIdx.x;
    int xcd = bid & 7;
    int q = bid >> 3;
    int cb = q & 127;                  // code block (64 codes)
    int wq = q >> 7;                   // window quad (0..3)
    int nb = cb * BN;
    int win0 = xcd + 32 * wq;
    int mb0 = win0 * BM;

    // ---- one-time stage: A-pack via async global_load_lds (16B, linear) ----
    {
        const char* src = Cpack + (size_t)cb * 32768;
#pragma unroll
        for (int it = 0; it < 8; ++it) {
            int off = it * 4096 + tid * 16;
            __builtin_amdgcn_global_load_lds(
                (const __attribute__((address_space(1))) void*)(src + off),
                (__attribute__((address_space(3))) void*)(lds + off),
                16, 0, 0);
        }
        if (tid < 64) ((float*)(lds + 32768))[tid] = cn[nb + tid];
    }

    const char* zb0 = Zpack + ((size_t)(mb0 >> 5) + 2 * w) * 16384 + lane * 16;

    // 2-deep register prefetch: pb[frag = n*2 + split][buf = kc&1]
    v8h pb[4][2];
#pragma unroll
    for (int n = 0; n < 2; ++n) {
        pb[2 * n + 0][0] = *(const v8h*)(zb0 + n * 16384);
        pb[2 * n + 1][0] = *(const v8h*)(zb0 + n * 16384 + 8192);
        pb[2 * n + 0][1] = *(const v8h*)(zb0 + n * 16384 + 1024);
        pb[2 * n + 1][1] = *(const v8h*)(zb0 + n * 16384 + 8192 + 1024);
    }

    __syncthreads();   // drains staging; LDS read-only after this

    const char* ab = lds + lane * 16;
    const float* cn_s = (const float*)(lds + 32768);

    int mb = mb0;
#pragma unroll 1
    for (int ww = 0; ww < WW; ++ww) {
        v16f acc[2][2];               // [mt codes][n token-groups]
#pragma unroll
        for (int mt = 0; mt < 2; ++mt)
#pragma unroll
            for (int n = 0; n < 2; ++n) acc[mt][n] = (v16f)0.f;

#pragma unroll
        for (int kc = 0; kc < 8; ++kc) {
            int curb = kc & 1;

            // hi-split A frags only (8 VGPR live)
            v8h Ah0 = *(const v8h*)(ab + (0 * 8 + kc) * 1024);       // mt0 hi
            v8h Ah1 = *(const v8h*)(ab + (1 * 8 + kc) * 1024);       // mt1 hi

            __builtin_amdgcn_s_setprio(1);
            // pass h*h
#pragma unroll
            for (int n = 0; n < 2; ++n)
                acc[0][n] = __builtin_amdgcn_mfma_f32_32x32x16_f16(Ah0, pb[2 * n][curb], acc[0][n], 0, 0, 0);
#pragma unroll
            for (int n = 0; n < 2; ++n)
                acc[1][n] = __builtin_amdgcn_mfma_f32_32x32x16_f16(Ah1, pb[2 * n][curb], acc[1][n], 0, 0, 0);
            // pass h*m
#pragma unroll
            for (int n = 0; n < 2; ++n)
                acc[0][n] = __builtin_amdgcn_mfma_f32_32x32x16_f16(Ah0, pb[2 * n + 1][curb], acc[0][n], 0, 0, 0);
#pragma unroll
            for (int n = 0; n < 2; ++n)
                acc[1][n] = __builtin_amdgcn_mfma_f32_32x32x16_f16(Ah1, pb[2 * n + 1][curb], acc[1][n], 0, 0, 0);
            __builtin_amdgcn_s_setprio(0);

            // lo-split A frags (hi frags dead now)
            v8h Am0 = *(const v8h*)(ab + (2 * 8 + kc) * 1024);       // mt0 lo
            v8h Am1 = *(const v8h*)(ab + (3 * 8 + kc) * 1024);       // mt1 lo

            __builtin_amdgcn_s_setprio(1);
            // pass m*h
#pragma unroll
            for (int n = 0; n < 2; ++n)
                acc[0][n] = __builtin_amdgcn_mfma_f32_32x32x16_f16(Am0, pb[2 * n][curb], acc[0][n], 0, 0, 0);
#pragma unroll
            for (int n = 0; n < 2; ++n)
                acc[1][n] = __builtin_amdgcn_mfma_f32_32x32x16_f16(Am1, pb[2 * n][curb], acc[1][n], 0, 0, 0);
            __builtin_amdgcn_s_setprio(0);

            // refill this buffer with kc+2; kc=6,7 pull kc=0,1 of the NEXT
            // window (handoff). Skipped at the last window (wave-uniform br).
            if (kc < 6) {
#pragma unroll
                for (int n = 0; n < 2; ++n) {
                    pb[2 * n + 0][curb] = *(const v8h*)(zb0 + n * 16384 + (kc + 2) * 1024);
                    pb[2 * n + 1][curb] = *(const v8h*)(zb0 + n * 16384 + 8192 + (kc + 2) * 1024);
                }
            } else if (ww < WW - 1) {
                const char* rb = zb0 + ZWIN_STRIDE;
                int knx = (kc + 2) & 7;
#pragma unroll
                for (int n = 0; n < 2; ++n) {
                    pb[2 * n + 0][curb] = *(const v8h*)(rb + n * 16384 + knx * 1024);
                    pb[2 * n + 1][curb] = *(const v8h*)(rb + n * 16384 + 8192 + knx * 1024);
                }
            }
        }

        // ---- epilogue: in-lane argmin per token group (zn-free: s'=cn-2dot,
        // token-constant zn cancels in every comparison) ----
        float best[2];
        int bi[2];
#pragma unroll
        for (int n = 0; n < 2; ++n) { best[n] = 3.4e38f; bi[n] = nb; }

#pragma unroll
        for (int mt = 0; mt < 2; ++mt) {
            float cnreg[16];
#pragma unroll
            for (int reg = 0; reg < 16; ++reg) {
                int mrow = 32 * mt + (reg & 3) + 8 * (reg >> 2) + 4 * half_id;
                cnreg[reg] = cn_s[mrow];
            }
#pragma unroll
            for (int n = 0; n < 2; ++n) {
#pragma unroll
                for (int reg = 0; reg < 16; ++reg) {
                    // ascending code order within half -> strict < keeps first-min
                    int mrow = 32 * mt + (reg & 3) + 8 * (reg >> 2) + 4 * half_id;
                    int code = nb + mrow;
                    float s = fmaf(acc[mt][n][reg], ACC_SCALE, cnreg[reg]);
                    if (s < best[n]) { best[n] = s; bi[n] = code; }
                }
            }
        }

        // cross-half combine + XCD-local packed atomicMin (no-return: the
        // wave continues; atomic latency overlaps the next window's K-loop)
#pragma unroll
        for (int n = 0; n < 2; ++n) {
            float ob = __shfl_xor(best[n], 32, 64);
            int oi = __shfl_xor(bi[n], 32, 64);
            if (ob < best[n] || (ob == best[n] && oi < bi[n])) { best[n] = ob; bi[n] = oi; }
            if ((n & 1) == half_id) {
                int tok = mb + w * 64 + n * 32 + (lane & 31);
                // monotone total-order encode of f32 (s' may be negative):
                // >=0: u^0x80000000 ; <0: u^0xFFFFFFFF. Equal s' -> equal key
                // -> min picks smaller code in low bits (first-min ties kept).
                unsigned ub = __float_as_uint(best[n]);
                unsigned key = ub ^ ((unsigned)(((int)ub) >> 31) | 0x80000000u);
                ull pk = ((ull)key << 32) | (unsigned)bi[n];
                atomicMin(&packed[tok], pk);
            }
        }

        zb0 += ZWIN_STRIDE;
        mb += 8 * BM;
    }
}

// ---------------- zq: unpack winner, out + counts + loss; last block scalars
__global__ __launch_bounds__(256) void zq_kernel(const float* __restrict__ Z,
                                                 const char* __restrict__ Cpack,
                                                 const ull* __restrict__ packed,
                                                 float* __restrict__ out,
                                                 int* __restrict__ counts,
                                                 float* __restrict__ lpart,
                                                 unsigned* __restrict__ done) {
    int gid = blockIdx.x * 256 + threadIdx.x;   // over T*D/4 float4s
    int t = gid >> 5;                           // 32 float4 per token
    int d4 = gid & 31;
    int idx = (int)(packed[t] & 0xFFFFFFFFull);
    if (d4 == 0) atomicAdd(&counts[idx], 1);

    // reconstruct c[d0..d0+3] = (ch + cm) * 2^-12 (exact sum: spans < 24 bits)
    int d0 = 4 * d4;
    int kc = d0 >> 4, hf = (d0 >> 3) & 1, j0 = d0 & 7;
    const char* cp = Cpack + (size_t)(idx >> 6) * 32768
                   + (size_t)((((idx >> 5) & 1) * 8 + kc) * 1024
                              + (hf * 32 + (idx & 31)) * 16 + j0 * 2);
    v4h h = *(const v4h*)(cp);
    v4h m = *(const v4h*)(cp + 16384);
    float4 cv;
    cv.x = ((float)h[0] + (float)m[0]) * DESCALE;
    cv.y = ((float)h[1] + (float)m[1]) * DESCALE;
    cv.z = ((float)h[2] + (float)m[2]) * DESCALE;
    cv.w = ((float)h[3] + (float)m[3]) * DESCALE;

    float4 zv = ((const float4*)Z)[gid];
    float dx = cv.x - zv.x, dy = cv.y - zv.y, dz = cv.z - zv.z, dw = cv.w - zv.w;
    float4 o;
    o.x = zv.x + dx;    // z + (z_q - z): match reference elementwise rounding
    o.y = zv.y + dy;
    o.z = zv.z + dz;
    o.w = zv.w + dw;
    ((float4*)out)[gid] = o;

    float ls = dx * dx + dy * dy + dz * dz + dw * dw;
#pragma unroll
    for (int off = 32; off > 0; off >>= 1) ls += __shfl_down(ls, off, 64);
    __shared__ float red[4];
    __shared__ int amLast;
    int lane = threadIdx.x & 63, w = threadIdx.x >> 6;
    if (lane == 0) red[w] = ls;
    __syncthreads();   // also drains this block's counts atomics (vmcnt(0))
    if (threadIdx.x == 0) {
        lpart[blockIdx.x] = (red[0] + red[1]) + (red[2] + red[3]);
        __threadfence();                       // lpart visible before done inc
        unsigned old = atomicAdd(done, 1u);
        amLast = (old == gridDim.x - 1);
    }
    __syncthreads();

    // ---- last block: scalars (replaces a whole dispatch). All other blocks'
    // counts atomics + lpart stores are ordered before their done-inc. ----
    if (amLast) {
        __threadfence();
        float s = 0.f;
        for (int i = threadIdx.x; i < K_CODE; i += 256) {
            float e = (float)counts[i] * (1.0f / (float)T_TOK);
            s += e * logf(e + 1e-8f);
        }
        float ls2 = 0.f;
        for (int i = threadIdx.x; i < 4096; i += 256) ls2 += lpart[i];
#pragma unroll
        for (int off = 32; off > 0; off >>= 1) {
            s += __shfl_down(s, off, 64);
            ls2 += __shfl_down(ls2, off, 64);
        }
        __shared__ float red2[8];
        if (lane == 0) { red2[w] = s; red2[4 + w] = ls2; }
        __syncthreads();
        if (threadIdx.x == 0) {
            float ssum = (red2[0] + red2[1]) + (red2[2] + red2[3]);
            float lsum = (red2[4] + red2[5]) + (red2[6] + red2[7]);
            out[(size_t)T_TOK * D_DIM + 0] = 1.25f * lsum / (float)((size_t)T_TOK * D_DIM);
            out[(size_t)T_TOK * D_DIM + 1] = expf(-ssum);
        }
    }
}

extern "C" void kernel_launch(void* const* d_in, const int* in_sizes, int n_in,
                              void* d_out, int out_size, void* d_ws, size_t ws_size,
                              hipStream_t stream) {
    const float* z   = (const float*)d_in[0];   // [8,4096,128]
    const float* emb = (const float*)d_in[1];   // [8192,128]
    const float* pw  = (const float*)d_in[2];   // [128,128]
    const float* pb  = (const float*)d_in[3];   // [128]
    float* out = (float*)d_out;

    // Zpack (f16 split fragments, 16.78 MB) lives in d_out: dead scratch until
    // zq_kernel overwrites d_out with the final z_q_st.
    char* Zpack = (char*)d_out;

    char* ws = (char*)d_ws;
    // layout (bytes):
    //   Cpack:  0        .. 4194304   (128 cb x 32768)
    //   cn:     4194304  .. 4227072   (8192 f32)
    //   lpart:  4227072  .. 4243456   (4096 f32)
    //   packed: 4358144  .. 4620288   (32768 u64)
    //   counts: 4620288  .. 4653056   (8192 i32)
    //   done:   4653056  .. 4653060   (1 u32)
    char*  Cpack  = ws + 0;
    float* cn     = (float*)(ws + 4194304);
    float* lpart  = (float*)(ws + 4227072);
    ull*   packed = (ull*)  (ws + 4358144);
    int*   counts = (int*)  (ws + 4620288);
    unsigned* done = (unsigned*)(ws + 4653056);

    prep_kernel<<<3072, 256, 0, stream>>>(emb, pw, pb, Cpack, cn, z, Zpack, packed, counts, done);
    argmin_kernel<<<(K_CODE / BN) * (T_TOK / BM) / WW, 256, 0, stream>>>(Zpack, Cpack, cn, packed);
    zq_kernel<<<(T_TOK * D_DIM / 4) / 256, 256, 0, stream>>>(z, Cpack, packed, out, counts, lpart, done);
}

// Round 7
// 395.587 us; speedup vs baseline: 2.8722x; 2.8722x over previous
//
#include <hip/hip_runtime.h>
#include <math.h>

#define T_TOK 32768
#define D_DIM 128
#define K_CODE 8192
#define BM 512              // tokens per window (argmin): 8 waves x 64
#define BN 64               // codes per tile
#define NCB 2               // cb tiles per block (double-buffered LDS)

typedef unsigned long long ull;
typedef _Float16 v8h __attribute__((ext_vector_type(8)));
typedef _Float16 v4h __attribute__((ext_vector_type(4)));
typedef float v16f __attribute__((ext_vector_type(16)));

#define SCALE 4096.0f        // 2^12: pushes f16 split residuals into normal range
#define DESCALE (1.0f / 4096.0f)
#define ACC_SCALE (-0x1p-23f)   // s' = cn - 2*dot (zn dropped: token-constant)

// Cpack layout (bytes): [cb=code/64][ (s*2+mt)*8+kc ][lane64][j8 f16]
// Zpack layout (bytes): [tb=token/32][ s ][ kc ][lane64][j8 f16]

// ---------------- proj: codebook row -> f16 split packs + cn ----------------
__global__ __launch_bounds__(256) void proj_kernel(const float* __restrict__ E,
                                                  const float* __restrict__ W,
                                                  const float* __restrict__ b,
                                                  char* __restrict__ Cpack,
                                                  float* __restrict__ cn) {
    int r = blockIdx.x * 4 + (threadIdx.x >> 6);
    int l = threadIdx.x & 63;          // 0..63
    const float4* E4 = (const float4*)(E + (size_t)r * D_DIM);
    const float4* WA = (const float4*)(W + (size_t)l * D_DIM);
    const float4* WB = (const float4*)(W + (size_t)(l + 64) * D_DIM);

    float4 aA = make_float4(0.f, 0.f, 0.f, 0.f);
    float4 aB = make_float4(0.f, 0.f, 0.f, 0.f);
#pragma unroll
    for (int dd = 0; dd < 32; ++dd) {
        float4 e = E4[dd];
        float4 wa = WA[dd], wb = WB[dd];
        aA.x = fmaf(e.x, wa.x, aA.x);
        aA.y = fmaf(e.y, wa.y, aA.y);
        aA.z = fmaf(e.z, wa.z, aA.z);
        aA.w = fmaf(e.w, wa.w, aA.w);
        aB.x = fmaf(e.x, wb.x, aB.x);
        aB.y = fmaf(e.y, wb.y, aB.y);
        aB.z = fmaf(e.z, wb.z, aB.z);
        aB.w = fmaf(e.w, wb.w, aB.w);
    }
    float vA = ((aA.x + aA.y) + (aA.z + aA.w)) + b[l];
    float vB = ((aB.x + aB.y) + (aB.z + aB.w)) + b[l + 64];

    char* cp = Cpack + (size_t)(r >> 6) * 32768;
    int mt = (r >> 5) & 1, rs = r & 31;
    {   // d = l
        int kc = l >> 4, hf = (l >> 3) & 1, j = l & 7;
        float f = vA * SCALE;
        _Float16 h = (_Float16)f;
        _Float16 m = (_Float16)(f - (float)h);
        size_t off = (size_t)((mt * 8 + kc) * 1024 + (hf * 32 + rs) * 16 + j * 2);
        *(_Float16*)(cp + off) = h;
        *(_Float16*)(cp + off + 16384) = m;
    }
    {   // d = l + 64
        int d = l + 64;
        int kc = d >> 4, hf = (d >> 3) & 1, j = d & 7;
        float f = vB * SCALE;
        _Float16 h = (_Float16)f;
        _Float16 m = (_Float16)(f - (float)h);
        size_t off = (size_t)((mt * 8 + kc) * 1024 + (hf * 32 + rs) * 16 + j * 2);
        *(_Float16*)(cp + off) = h;
        *(_Float16*)(cp + off + 16384) = m;
    }

    float s = vA * vA + vB * vB;
#pragma unroll
    for (int off = 32; off > 0; off >>= 1) s += __shfl_down(s, off, 64);
    if (l == 0) cn[r] = s;
}

// ---------------- prep_z: z -> f16 split packs + fused inits ----------------
__global__ __launch_bounds__(256) void prep_z_kernel(const float* __restrict__ Z,
                                                     char* __restrict__ Zpack,
                                                     ull* __restrict__ packed,
                                                     int* __restrict__ counts) {
    int tb = blockIdx.x;          // 32-token group
    int tid = threadIdx.x;
    int lane = tid & 63;
    int w = tid >> 6;

    // fused inits (zn kernel removed entirely: argmin no longer needs |z|^2)
    int g = blockIdx.x * 256 + tid;
    if (g < T_TOK) packed[g] = ~0ull;
    if (g < K_CODE) counts[g] = 0;

    char* zp = Zpack + (size_t)tb * 16384;
#pragma unroll
    for (int kq = 0; kq < 2; ++kq) {
        int kc = 2 * w + kq;
        const float* src = Z + (size_t)(tb * 32 + (lane & 31)) * D_DIM
                             + kc * 16 + (lane >> 5) * 8;
        float4 a = *(const float4*)(src);
        float4 c = *(const float4*)(src + 4);
        float vals[8] = {a.x, a.y, a.z, a.w, c.x, c.y, c.z, c.w};
        v8h h, m;
#pragma unroll
        for (int j = 0; j < 8; ++j) {
            float f = vals[j] * SCALE;
            _Float16 hh = (_Float16)f;
            h[j] = hh;
            m[j] = (_Float16)(f - (float)hh);
        }
        *(v8h*)(zp + (size_t)(kc * 1024 + lane * 16)) = h;
        *(v8h*)(zp + (size_t)(8192 + kc * 1024 + lane * 16)) = m;
    }
}

// ---------------- MFMA argmin: 2 cb-tiles / block, double-buffered LDS ------
// R16 post-mortem: R6's window-axis persistence destroyed L2 sharing (FETCH
// 1.9 GB): sharing requires the WINDOW in bid HIGH bits (co-resident blocks
// read one window), never in intra-block time. R5's residual 49% idle =
// per-block stage+drain head and epilogue tail convoying across resident
// blocks. R7 amortizes the head along the CODE axis, window untouched:
//  - 8-wave block owns window win=bid>>6 (high bits: ~8 windows resident ->
//    L2-hot) and TWO cb tiles, LDS double-buffered (2x32KB = exactly 64KB).
//  - tile1's async global_load_lds stage is issued right after the first
//    barrier and lands under K-loop(tile0): one exposed stage per block, the
//    second barrier drains an already-complete transfer.
//  - both tiles share the same window -> K1's B-refills re-read K0's bytes
//    (L1/L2-hot), and the (kc+2)&7 handoff at kc=6,7 of tile0 pre-warms pb
//    for tile1 (R2's verified rotation trick).
//  - best/bi persist across tiles; ascending tile order + strict < keeps
//    exact first-min semantics; ONE atomic phase at block end (half the
//    atomics, none in the K-loop shadow).
// LDS (2 blocks x 64KB) is the occupancy cap -> register pressure has slack.
__global__ __launch_bounds__(512, 2) void argmin_kernel(const char* __restrict__ Zpack,
                                                        const char* __restrict__ Cpack,
                                                        const float* __restrict__ cn,
                                                        ull* __restrict__ packed) {
    __shared__ __align__(16) char lds[NCB][32768];   // 64 KB: static cap

    int tid = threadIdx.x;
    int lane = tid & 63;
    int w = tid >> 6;                  // 0..7
    int half_id = lane >> 5;

    // win in HIGH bits: changes every 64 bids ~= co-residency granularity.
    int bid = blockIdx.x;
    int cbp = bid & 63;                // cb pair (codes cbp*128 .. +127)
    int win = bid >> 6;                // token window (512 tokens)
    int cb0 = cbp * 2;
    int mb = win * BM;

    // ---- stage tile 0 into lds[0] (async, 16B, linear) ----
    {
        const char* src = Cpack + (size_t)cb0 * 32768;
#pragma unroll
        for (int it = 0; it < 4; ++it) {
            int off = it * 8192 + tid * 16;
            __builtin_amdgcn_global_load_lds(
                (const __attribute__((address_space(1))) void*)(src + off),
                (__attribute__((address_space(3))) void*)(&lds[0][0] + off),
                16, 0, 0);
        }
    }

    int tbw = (mb >> 5) + 2 * w;       // wave w owns tb groups 2w, 2w+1
    const char* zb0 = Zpack + (size_t)tbw * 16384 + lane * 16;

    // 2-deep register prefetch: pb[frag = n*2 + split][buf = kc&1]
    v8h pb[4][2];
#pragma unroll
    for (int n = 0; n < 2; ++n) {
        pb[2 * n + 0][0] = *(const v8h*)(zb0 + n * 16384);
        pb[2 * n + 1][0] = *(const v8h*)(zb0 + n * 16384 + 8192);
        pb[2 * n + 0][1] = *(const v8h*)(zb0 + n * 16384 + 1024);
        pb[2 * n + 1][1] = *(const v8h*)(zb0 + n * 16384 + 8192 + 1024);
    }

    __syncthreads();   // drains tile-0 staging; lds[0] read-only after this

    // issue tile 1's stage NOW: lands under K-loop(tile 0)
    {
        const char* src = Cpack + (size_t)(cb0 + 1) * 32768;
#pragma unroll
        for (int it = 0; it < 4; ++it) {
            int off = it * 8192 + tid * 16;
            __builtin_amdgcn_global_load_lds(
                (const __attribute__((address_space(1))) void*)(src + off),
                (__attribute__((address_space(3))) void*)(&lds[1][0] + off),
                16, 0, 0);
        }
    }

    // running argmin across both tiles (ascending code order -> first-min)
    float best[2];
    int bi[2];
#pragma unroll
    for (int n = 0; n < 2; ++n) { best[n] = 3.4e38f; bi[n] = cb0 * BN; }

#pragma unroll
    for (int t = 0; t < NCB; ++t) {
        const char* ab = &lds[t][0] + lane * 16;
        int nb = (cb0 + t) * BN;

        v16f acc[2][2];               // [mt codes][n token-groups]
#pragma unroll
        for (int mt = 0; mt < 2; ++mt)
#pragma unroll
            for (int n = 0; n < 2; ++n) acc[mt][n] = (v16f)0.f;

#pragma unroll
        for (int kc = 0; kc < 8; ++kc) {
            int curb = kc & 1;

            // hi-split A frags only (8 VGPR live)
            v8h Ah0 = *(const v8h*)(ab + (0 * 8 + kc) * 1024);       // mt0 hi
            v8h Ah1 = *(const v8h*)(ab + (1 * 8 + kc) * 1024);       // mt1 hi

            __builtin_amdgcn_s_setprio(1);
            // pass h*h
#pragma unroll
            for (int n = 0; n < 2; ++n)
                acc[0][n] = __builtin_amdgcn_mfma_f32_32x32x16_f16(Ah0, pb[2 * n][curb], acc[0][n], 0, 0, 0);
#pragma unroll
            for (int n = 0; n < 2; ++n)
                acc[1][n] = __builtin_amdgcn_mfma_f32_32x32x16_f16(Ah1, pb[2 * n][curb], acc[1][n], 0, 0, 0);
            // pass h*m
#pragma unroll
            for (int n = 0; n < 2; ++n)
                acc[0][n] = __builtin_amdgcn_mfma_f32_32x32x16_f16(Ah0, pb[2 * n + 1][curb], acc[0][n], 0, 0, 0);
#pragma unroll
            for (int n = 0; n < 2; ++n)
                acc[1][n] = __builtin_amdgcn_mfma_f32_32x32x16_f16(Ah1, pb[2 * n + 1][curb], acc[1][n], 0, 0, 0);
            __builtin_amdgcn_s_setprio(0);

            // lo-split A frags (hi frags dead now)
            v8h Am0 = *(const v8h*)(ab + (2 * 8 + kc) * 1024);       // mt0 lo
            v8h Am1 = *(const v8h*)(ab + (3 * 8 + kc) * 1024);       // mt1 lo

            __builtin_amdgcn_s_setprio(1);
            // pass m*h
#pragma unroll
            for (int n = 0; n < 2; ++n)
                acc[0][n] = __builtin_amdgcn_mfma_f32_32x32x16_f16(Am0, pb[2 * n][curb], acc[0][n], 0, 0, 0);
#pragma unroll
            for (int n = 0; n < 2; ++n)
                acc[1][n] = __builtin_amdgcn_mfma_f32_32x32x16_f16(Am1, pb[2 * n][curb], acc[1][n], 0, 0, 0);
            __builtin_amdgcn_s_setprio(0);

            // refill with (kc+2)&7: at kc=6,7 of tile 0 this pre-warms kc=0,1
            // for tile 1 (same window -> same bytes, L1/L2-hot). Skipped at
            // the last tile's kc=6,7 (compile-time, wave-uniform).
            if (kc < 6 || t + 1 < NCB) {
                int knx = (kc + 2) & 7;
#pragma unroll
                for (int n = 0; n < 2; ++n) {
                    pb[2 * n + 0][curb] = *(const v8h*)(zb0 + n * 16384 + knx * 1024);
                    pb[2 * n + 1][curb] = *(const v8h*)(zb0 + n * 16384 + 8192 + knx * 1024);
                }
            }
        }

        if (t == 0) __syncthreads();   // tile-1 stage landed long ago: cheap

        // ---- epilogue: fold this tile into the running per-token argmin
        // (zn-free: s' = cn - 2dot; token-constant zn cancels) ----
#pragma unroll
        for (int mt = 0; mt < 2; ++mt) {
            float cnreg[16];
#pragma unroll
            for (int reg = 0; reg < 16; ++reg) {
                int mrow = 32 * mt + (reg & 3) + 8 * (reg >> 2) + 4 * half_id;
                cnreg[reg] = __ldg(&cn[nb + mrow]);   // 256B region, L1-hot
            }
#pragma unroll
            for (int n = 0; n < 2; ++n) {
#pragma unroll
                for (int reg = 0; reg < 16; ++reg) {
                    // ascending code order + strict < keeps first-min
                    int mrow = 32 * mt + (reg & 3) + 8 * (reg >> 2) + 4 * half_id;
                    int code = nb + mrow;
                    float s = fmaf(acc[mt][n][reg], ACC_SCALE, cnreg[reg]);
                    if (s < best[n]) { best[n] = s; bi[n] = code; }
                }
            }
        }
    }

    // ---- final: cross-half combine + ONE packed atomicMin per token ----
#pragma unroll
    for (int n = 0; n < 2; ++n) {
        float ob = __shfl_xor(best[n], 32, 64);
        int oi = __shfl_xor(bi[n], 32, 64);
        if (ob < best[n] || (ob == best[n] && oi < bi[n])) { best[n] = ob; bi[n] = oi; }
        if ((n & 1) == half_id) {
            int tok = mb + w * 64 + n * 32 + (lane & 31);
            // monotone total-order encode of f32 (s' may be negative):
            // >=0: u^0x80000000 ; <0: u^0xFFFFFFFF. Equal s' -> equal key ->
            // min picks smaller code in low bits (first-min ties preserved).
            unsigned ub = __float_as_uint(best[n]);
            unsigned key = ub ^ ((unsigned)(((int)ub) >> 31) | 0x80000000u);
            ull pk = ((ull)key << 32) | (unsigned)bi[n];
            atomicMin(&packed[tok], pk);
        }
    }
}

// ---------------- zq: unpack winner, reconstruct code row, out + counts + loss
__global__ __launch_bounds__(256) void zq_kernel(const float* __restrict__ Z,
                                                 const char* __restrict__ Cpack,
                                                 const ull* __restrict__ packed,
                                                 float* __restrict__ out,
                                                 int* __restrict__ counts,
                                                 float* __restrict__ lpart) {
    int gid = blockIdx.x * 256 + threadIdx.x;   // over T*D/4 float4s
    int t = gid >> 5;                           // 32 float4 per token
    int d4 = gid & 31;
    int idx = (int)(packed[t] & 0xFFFFFFFFull);
    if (d4 == 0) atomicAdd(&counts[idx], 1);

    // reconstruct c[d0..d0+3] = (ch + cm) * 2^-12 (exact sum: spans < 24 bits)
    int d0 = 4 * d4;
    int kc = d0 >> 4, hf = (d0 >> 3) & 1, j0 = d0 & 7;
    const char* cp = Cpack + (size_t)(idx >> 6) * 32768
                   + (size_t)((((idx >> 5) & 1) * 8 + kc) * 1024
                              + (hf * 32 + (idx & 31)) * 16 + j0 * 2);
    v4h h = *(const v4h*)(cp);
    v4h m = *(const v4h*)(cp + 16384);
    float4 cv;
    cv.x = ((float)h[0] + (float)m[0]) * DESCALE;
    cv.y = ((float)h[1] + (float)m[1]) * DESCALE;
    cv.z = ((float)h[2] + (float)m[2]) * DESCALE;
    cv.w = ((float)h[3] + (float)m[3]) * DESCALE;

    float4 zv = ((const float4*)Z)[gid];
    float dx = cv.x - zv.x, dy = cv.y - zv.y, dz = cv.z - zv.z, dw = cv.w - zv.w;
    float4 o;
    o.x = zv.x + dx;    // z + (z_q - z): match reference elementwise rounding
    o.y = zv.y + dy;
    o.z = zv.z + dz;
    o.w = zv.w + dw;
    ((float4*)out)[gid] = o;

    float ls = dx * dx + dy * dy + dz * dz + dw * dw;
#pragma unroll
    for (int off = 32; off > 0; off >>= 1) ls += __shfl_down(ls, off, 64);
    __shared__ float red[4];
    int lane = threadIdx.x & 63, w = threadIdx.x >> 6;
    if (lane == 0) red[w] = ls;
    __syncthreads();
    // per-block partial store: no same-address atomic serialization
    if (threadIdx.x == 0) lpart[blockIdx.x] = (red[0] + red[1]) + (red[2] + red[3]);
}

// ---------------- scalars: commit_loss (from partials), perplexity ----------
__global__ __launch_bounds__(256) void scalars_kernel(const int* __restrict__ counts,
                                                      const float* __restrict__ lpart,
                                                      float* __restrict__ out) {
    float s = 0.f;
    for (int i = threadIdx.x; i < K_CODE; i += 256) {
        float e = (float)counts[i] * (1.0f / (float)T_TOK);
        s += e * logf(e + 1e-8f);
    }
    float ls = 0.f;
    for (int i = threadIdx.x; i < 4096; i += 256) ls += lpart[i];
#pragma unroll
    for (int off = 32; off > 0; off >>= 1) {
        s += __shfl_down(s, off, 64);
        ls += __shfl_down(ls, off, 64);
    }
    __shared__ float red[8];
    int lane = threadIdx.x & 63, w = threadIdx.x >> 6;
    if (lane == 0) { red[w] = s; red[4 + w] = ls; }
    __syncthreads();
    if (threadIdx.x == 0) {
        float ssum = (red[0] + red[1]) + (red[2] + red[3]);
        float lsum = (red[4] + red[5]) + (red[6] + red[7]);
        out[(size_t)T_TOK * D_DIM + 0] = 1.25f * lsum / (float)((size_t)T_TOK * D_DIM);
        out[(size_t)T_TOK * D_DIM + 1] = expf(-ssum);
    }
}

extern "C" void kernel_launch(void* const* d_in, const int* in_sizes, int n_in,
                              void* d_out, int out_size, void* d_ws, size_t ws_size,
                              hipStream_t stream) {
    const float* z   = (const float*)d_in[0];   // [8,4096,128]
    const float* emb = (const float*)d_in[1];   // [8192,128]
    const float* pw  = (const float*)d_in[2];   // [128,128]
    const float* pb  = (const float*)d_in[3];   // [128]
    float* out = (float*)d_out;

    // Zpack (f16 split fragments, 16.78 MB) lives in d_out: dead scratch until
    // zq_kernel overwrites d_out with the final z_q_st.
    char* Zpack = (char*)d_out;

    char* ws = (char*)d_ws;
    // layout (bytes):
    //   Cpack:  0        .. 4194304   (128 cb x 32768)
    //   cn:     4194304  .. 4227072   (8192 f32)
    //   lpart:  4227072  .. 4243456   (4096 f32)
    //   packed: 4358144  .. 4620288   (32768 u64)
    //   counts: 4620288  .. 4653056   (8192 i32)
    char*  Cpack  = ws + 0;
    float* cn     = (float*)(ws + 4194304);
    float* lpart  = (float*)(ws + 4227072);
    ull*   packed = (ull*)  (ws + 4358144);
    int*   counts = (int*)  (ws + 4620288);

    proj_kernel<<<K_CODE / 4, 256, 0, stream>>>(emb, pw, pb, Cpack, cn);
    prep_z_kernel<<<T_TOK / 32, 256, 0, stream>>>(z, Zpack, packed, counts);
    argmin_kernel<<<(K_CODE / BN / NCB) * (T_TOK / BM), 512, 0, stream>>>(Zpack, Cpack, cn, packed);
    zq_kernel<<<(T_TOK * D_DIM / 4) / 256, 256, 0, stream>>>(z, Cpack, packed, out, counts, lpart);
    scalars_kernel<<<1, 256, 0, stream>>>(counts, lpart, out);
}

// Round 8
// 369.346 us; speedup vs baseline: 3.0763x; 1.0710x over previous
//
#include <hip/hip_runtime.h>
#include <math.h>

#define T_TOK 32768
#define D_DIM 128
#define K_CODE 8192
#define BM 256              // tokens per block (argmin): 4 waves x 64
#define BN 64               // codes per block (argmin)

typedef unsigned long long ull;
typedef _Float16 v8h __attribute__((ext_vector_type(8)));
typedef _Float16 v4h __attribute__((ext_vector_type(4)));
typedef float v16f __attribute__((ext_vector_type(16)));

#define SCALE 4096.0f        // 2^12: pushes f16 split residuals into normal range
#define DESCALE (1.0f / 4096.0f)
#define ACC_SCALE (-0x1p-23f)   // s' = cn - 2*dot (zn dropped: token-constant)

// Cpack layout (bytes): [cb=code/64][ (s*2+mt)*8+kc ][lane64][j8 f16]
// Zpack layout (bytes): [tb=token/32][ s ][ kc ][lane64][j8 f16]

// ---------------- proj: codebook row -> f16 split packs + cn ----------------
__global__ __launch_bounds__(256) void proj_kernel(const float* __restrict__ E,
                                                  const float* __restrict__ W,
                                                  const float* __restrict__ b,
                                                  char* __restrict__ Cpack,
                                                  float* __restrict__ cn) {
    int r = blockIdx.x * 4 + (threadIdx.x >> 6);
    int l = threadIdx.x & 63;          // 0..63
    const float4* E4 = (const float4*)(E + (size_t)r * D_DIM);
    const float4* WA = (const float4*)(W + (size_t)l * D_DIM);
    const float4* WB = (const float4*)(W + (size_t)(l + 64) * D_DIM);

    float4 aA = make_float4(0.f, 0.f, 0.f, 0.f);
    float4 aB = make_float4(0.f, 0.f, 0.f, 0.f);
#pragma unroll
    for (int dd = 0; dd < 32; ++dd) {
        float4 e = E4[dd];
        float4 wa = WA[dd], wb = WB[dd];
        aA.x = fmaf(e.x, wa.x, aA.x);
        aA.y = fmaf(e.y, wa.y, aA.y);
        aA.z = fmaf(e.z, wa.z, aA.z);
        aA.w = fmaf(e.w, wa.w, aA.w);
        aB.x = fmaf(e.x, wb.x, aB.x);
        aB.y = fmaf(e.y, wb.y, aB.y);
        aB.z = fmaf(e.z, wb.z, aB.z);
        aB.w = fmaf(e.w, wb.w, aB.w);
    }
    float vA = ((aA.x + aA.y) + (aA.z + aA.w)) + b[l];
    float vB = ((aB.x + aB.y) + (aB.z + aB.w)) + b[l + 64];

    char* cp = Cpack + (size_t)(r >> 6) * 32768;
    int mt = (r >> 5) & 1, rs = r & 31;
    {   // d = l
        int kc = l >> 4, hf = (l >> 3) & 1, j = l & 7;
        float f = vA * SCALE;
        _Float16 h = (_Float16)f;
        _Float16 m = (_Float16)(f - (float)h);
        size_t off = (size_t)((mt * 8 + kc) * 1024 + (hf * 32 + rs) * 16 + j * 2);
        *(_Float16*)(cp + off) = h;
        *(_Float16*)(cp + off + 16384) = m;
    }
    {   // d = l + 64
        int d = l + 64;
        int kc = d >> 4, hf = (d >> 3) & 1, j = d & 7;
        float f = vB * SCALE;
        _Float16 h = (_Float16)f;
        _Float16 m = (_Float16)(f - (float)h);
        size_t off = (size_t)((mt * 8 + kc) * 1024 + (hf * 32 + rs) * 16 + j * 2);
        *(_Float16*)(cp + off) = h;
        *(_Float16*)(cp + off + 16384) = m;
    }

    float s = vA * vA + vB * vB;
#pragma unroll
    for (int off = 32; off > 0; off >>= 1) s += __shfl_down(s, off, 64);
    if (l == 0) cn[r] = s;
}

// ---------------- prep_z: z -> f16 split packs + fused inits ----------------
__global__ __launch_bounds__(256) void prep_z_kernel(const float* __restrict__ Z,
                                                     char* __restrict__ Zpack,
                                                     ull* __restrict__ packed,
                                                     int* __restrict__ counts) {
    int tb = blockIdx.x;          // 32-token group
    int tid = threadIdx.x;
    int lane = tid & 63;
    int w = tid >> 6;

    // fused inits (zn kernel removed entirely: argmin no longer needs |z|^2)
    int g = blockIdx.x * 256 + tid;
    if (g < T_TOK) packed[g] = ~0ull;
    if (g < K_CODE) counts[g] = 0;

    char* zp = Zpack + (size_t)tb * 16384;
#pragma unroll
    for (int kq = 0; kq < 2; ++kq) {
        int kc = 2 * w + kq;
        const float* src = Z + (size_t)(tb * 32 + (lane & 31)) * D_DIM
                             + kc * 16 + (lane >> 5) * 8;
        float4 a = *(const float4*)(src);
        float4 c = *(const float4*)(src + 4);
        float vals[8] = {a.x, a.y, a.z, a.w, c.x, c.y, c.z, c.w};
        v8h h, m;
#pragma unroll
        for (int j = 0; j < 8; ++j) {
            float f = vals[j] * SCALE;
            _Float16 hh = (_Float16)f;
            h[j] = hh;
            m[j] = (_Float16)(f - (float)hh);
        }
        *(v8h*)(zp + (size_t)(kc * 1024 + lane * 16)) = h;
        *(v8h*)(zp + (size_t)(8192 + kc * 1024 + lane * 16)) = m;
    }
}

// ---------------- MFMA argmin: 3-buffer deep B-prefetch ---------------------
// R17 post-mortem chain: R0/R4/R5 all pin at 207us across 8->16 waves/CU;
// R3/R7 (big barrier-locked blocks) are worse. Occupancy-insensitive wall +
// per-wave-identical structure => per-wave K-loop stall: the 2-buffer pb
// refill issues at the BOTTOM of the kc body and is consumed 12 MFMA issues
// later (~300-400 cyc at 3-4 wave interleave) -- below L2-loaded latency
// (~500-900 cyc), so every kc eats a vmcnt stall. Fix: 3-buffer rotation
// (buf = kc%3): slot (kc+2)%3 was consumed at kc-1, so its refill issues at
// the TOP of the body, giving 2 full bodies (~600-800 cyc) of distance.
// Cost: pb 32->48 VGPR => ~144 unified => 3 waves/SIMD; R4 showed 10-12
// waves == 16 waves at this structure, so the give-back should be free.
// Passes, epilogue arithmetic, swizzle, tie-breaks identical to R5.
__global__ __launch_bounds__(256, 3) void argmin_kernel(const char* __restrict__ Zpack,
                                                        const char* __restrict__ Cpack,
                                                        const float* __restrict__ cn,
                                                        ull* __restrict__ packed) {
    __shared__ __align__(16) char lds[33024];   // 32768 A-pack + 256 cn

    int tid = threadIdx.x;
    int lane = tid & 63;
    int w = tid >> 6;                  // 0..3
    int half_id = lane >> 5;

    // XCD swizzle (R5-identical): window in HIGH bits of q -> co-resident
    // blocks share one window (L2-hot Zpack); Cpack cycles L2-resident.
    int bid = blockIdx.x;
    int xcd = bid & 7;
    int q = bid >> 3;
    int cb = q & 127;                  // code block (64 codes)
    int win = xcd + 8 * (q >> 7);      // token window (256 tokens)
    int nb = cb * BN;
    int mb = win * BM;

    // ---- one-time stage: A-pack via async global_load_lds (16B, linear) ----
    {
        const char* src = Cpack + (size_t)cb * 32768;
#pragma unroll
        for (int it = 0; it < 8; ++it) {
            int off = it * 4096 + tid * 16;
            __builtin_amdgcn_global_load_lds(
                (const __attribute__((address_space(1))) void*)(src + off),
                (__attribute__((address_space(3))) void*)(lds + off),
                16, 0, 0);
        }
        if (tid < 64) ((float*)(lds + 32768))[tid] = cn[nb + tid];
    }

    int tbw = (mb >> 5) + 2 * w;       // wave w owns token groups 2w, 2w+1
    const char* zb0 = Zpack + (size_t)tbw * 16384 + lane * 16;

    // 3-slot register prefetch: pb[frag = n*2 + split][slot = kc%3]
    v8h pb[4][3];
#pragma unroll
    for (int n = 0; n < 2; ++n) {
        pb[2 * n + 0][0] = *(const v8h*)(zb0 + n * 16384);
        pb[2 * n + 1][0] = *(const v8h*)(zb0 + n * 16384 + 8192);
        pb[2 * n + 0][1] = *(const v8h*)(zb0 + n * 16384 + 1024);
        pb[2 * n + 1][1] = *(const v8h*)(zb0 + n * 16384 + 8192 + 1024);
    }

    __syncthreads();   // drains staging; LDS read-only after this

    const char* ab = lds + lane * 16;
    const float* cn_s = (const float*)(lds + 32768);

    v16f acc[2][2];               // [mt codes][n token-groups]
#pragma unroll
    for (int mt = 0; mt < 2; ++mt)
#pragma unroll
        for (int n = 0; n < 2; ++n) acc[mt][n] = (v16f)0.f;

#pragma unroll
    for (int kc = 0; kc < 8; ++kc) {
        int curb = kc % 3;

        // deep refill FIRST: slot (kc+2)%3 was consumed at kc-1; its new data
        // is consumed at kc+2 -> 2 full bodies of latency headroom.
        if (kc < 6) {
            int slot = (kc + 2) % 3;
#pragma unroll
            for (int n = 0; n < 2; ++n) {
                pb[2 * n + 0][slot] = *(const v8h*)(zb0 + n * 16384 + (kc + 2) * 1024);
                pb[2 * n + 1][slot] = *(const v8h*)(zb0 + n * 16384 + 8192 + (kc + 2) * 1024);
            }
        }

        // hi-split A frags only (8 VGPR live)
        v8h Ah0 = *(const v8h*)(ab + (0 * 8 + kc) * 1024);       // mt0 hi
        v8h Ah1 = *(const v8h*)(ab + (1 * 8 + kc) * 1024);       // mt1 hi

        __builtin_amdgcn_s_setprio(1);
        // pass h*h
#pragma unroll
        for (int n = 0; n < 2; ++n)
            acc[0][n] = __builtin_amdgcn_mfma_f32_32x32x16_f16(Ah0, pb[2 * n][curb], acc[0][n], 0, 0, 0);
#pragma unroll
        for (int n = 0; n < 2; ++n)
            acc[1][n] = __builtin_amdgcn_mfma_f32_32x32x16_f16(Ah1, pb[2 * n][curb], acc[1][n], 0, 0, 0);
        // pass h*m
#pragma unroll
        for (int n = 0; n < 2; ++n)
            acc[0][n] = __builtin_amdgcn_mfma_f32_32x32x16_f16(Ah0, pb[2 * n + 1][curb], acc[0][n], 0, 0, 0);
#pragma unroll
        for (int n = 0; n < 2; ++n)
            acc[1][n] = __builtin_amdgcn_mfma_f32_32x32x16_f16(Ah1, pb[2 * n + 1][curb], acc[1][n], 0, 0, 0);
        __builtin_amdgcn_s_setprio(0);

        // lo-split A frags (hi frags dead now)
        v8h Am0 = *(const v8h*)(ab + (2 * 8 + kc) * 1024);       // mt0 lo
        v8h Am1 = *(const v8h*)(ab + (3 * 8 + kc) * 1024);       // mt1 lo

        __builtin_amdgcn_s_setprio(1);
        // pass m*h
#pragma unroll
        for (int n = 0; n < 2; ++n)
            acc[0][n] = __builtin_amdgcn_mfma_f32_32x32x16_f16(Am0, pb[2 * n][curb], acc[0][n], 0, 0, 0);
#pragma unroll
        for (int n = 0; n < 2; ++n)
            acc[1][n] = __builtin_amdgcn_mfma_f32_32x32x16_f16(Am1, pb[2 * n][curb], acc[1][n], 0, 0, 0);
        __builtin_amdgcn_s_setprio(0);
    }

    // ---- epilogue: in-lane argmin per token group (zn-free: s' = cn - 2dot,
    // token-constant zn cancels in every comparison) ----
    float best[2];
    int bi[2];
#pragma unroll
    for (int n = 0; n < 2; ++n) { best[n] = 3.4e38f; bi[n] = nb; }

#pragma unroll
    for (int mt = 0; mt < 2; ++mt) {
        float cnreg[16];
#pragma unroll
        for (int reg = 0; reg < 16; ++reg) {
            int mrow = 32 * mt + (reg & 3) + 8 * (reg >> 2) + 4 * half_id;
            cnreg[reg] = cn_s[mrow];
        }
#pragma unroll
        for (int n = 0; n < 2; ++n) {
#pragma unroll
            for (int reg = 0; reg < 16; ++reg) {
                // ascending code order within half -> strict < keeps first-min
                int mrow = 32 * mt + (reg & 3) + 8 * (reg >> 2) + 4 * half_id;
                int code = nb + mrow;
                float s = fmaf(acc[mt][n][reg], ACC_SCALE, cnreg[reg]);
                if (s < best[n]) { best[n] = s; bi[n] = code; }
            }
        }
    }

    // cross-half combine + XCD-local packed atomicMin
#pragma unroll
    for (int n = 0; n < 2; ++n) {
        float ob = __shfl_xor(best[n], 32, 64);
        int oi = __shfl_xor(bi[n], 32, 64);
        if (ob < best[n] || (ob == best[n] && oi < bi[n])) { best[n] = ob; bi[n] = oi; }
        if ((n & 1) == half_id) {
            int tok = mb + w * 64 + n * 32 + (lane & 31);
            // monotone total-order encode of f32 (s' may be negative):
            // >=0: u^0x80000000 ; <0: u^0xFFFFFFFF. Equal s' -> equal key ->
            // min picks smaller code in low bits (first-min ties preserved).
            unsigned ub = __float_as_uint(best[n]);
            unsigned key = ub ^ ((unsigned)(((int)ub) >> 31) | 0x80000000u);
            ull pk = ((ull)key << 32) | (unsigned)bi[n];
            atomicMin(&packed[tok], pk);
        }
    }
}

// ---------------- zq: unpack winner, reconstruct code row, out + counts + loss
__global__ __launch_bounds__(256) void zq_kernel(const float* __restrict__ Z,
                                                 const char* __restrict__ Cpack,
                                                 const ull* __restrict__ packed,
                                                 float* __restrict__ out,
                                                 int* __restrict__ counts,
                                                 float* __restrict__ lpart) {
    int gid = blockIdx.x * 256 + threadIdx.x;   // over T*D/4 float4s
    int t = gid >> 5;                           // 32 float4 per token
    int d4 = gid & 31;
    int idx = (int)(packed[t] & 0xFFFFFFFFull);
    if (d4 == 0) atomicAdd(&counts[idx], 1);

    // reconstruct c[d0..d0+3] = (ch + cm) * 2^-12 (exact sum: spans < 24 bits)
    int d0 = 4 * d4;
    int kc = d0 >> 4, hf = (d0 >> 3) & 1, j0 = d0 & 7;
    const char* cp = Cpack + (size_t)(idx >> 6) * 32768
                   + (size_t)((((idx >> 5) & 1) * 8 + kc) * 1024
                              + (hf * 32 + (idx & 31)) * 16 + j0 * 2);
    v4h h = *(const v4h*)(cp);
    v4h m = *(const v4h*)(cp + 16384);
    float4 cv;
    cv.x = ((float)h[0] + (float)m[0]) * DESCALE;
    cv.y = ((float)h[1] + (float)m[1]) * DESCALE;
    cv.z = ((float)h[2] + (float)m[2]) * DESCALE;
    cv.w = ((float)h[3] + (float)m[3]) * DESCALE;

    float4 zv = ((const float4*)Z)[gid];
    float dx = cv.x - zv.x, dy = cv.y - zv.y, dz = cv.z - zv.z, dw = cv.w - zv.w;
    float4 o;
    o.x = zv.x + dx;    // z + (z_q - z): match reference elementwise rounding
    o.y = zv.y + dy;
    o.z = zv.z + dz;
    o.w = zv.w + dw;
    ((float4*)out)[gid] = o;

    float ls = dx * dx + dy * dy + dz * dz + dw * dw;
#pragma unroll
    for (int off = 32; off > 0; off >>= 1) ls += __shfl_down(ls, off, 64);
    __shared__ float red[4];
    int lane = threadIdx.x & 63, w = threadIdx.x >> 6;
    if (lane == 0) red[w] = ls;
    __syncthreads();
    // per-block partial store: no same-address atomic serialization
    if (threadIdx.x == 0) lpart[blockIdx.x] = (red[0] + red[1]) + (red[2] + red[3]);
}

// ---------------- scalars: commit_loss (from partials), perplexity ----------
__global__ __launch_bounds__(256) void scalars_kernel(const int* __restrict__ counts,
                                                      const float* __restrict__ lpart,
                                                      float* __restrict__ out) {
    float s = 0.f;
    for (int i = threadIdx.x; i < K_CODE; i += 256) {
        float e = (float)counts[i] * (1.0f / (float)T_TOK);
        s += e * logf(e + 1e-8f);
    }
    float ls = 0.f;
    for (int i = threadIdx.x; i < 4096; i += 256) ls += lpart[i];
#pragma unroll
    for (int off = 32; off > 0; off >>= 1) {
        s += __shfl_down(s, off, 64);
        ls += __shfl_down(ls, off, 64);
    }
    __shared__ float red[8];
    int lane = threadIdx.x & 63, w = threadIdx.x >> 6;
    if (lane == 0) { red[w] = s; red[4 + w] = ls; }
    __syncthreads();
    if (threadIdx.x == 0) {
        float ssum = (red[0] + red[1]) + (red[2] + red[3]);
        float lsum = (red[4] + red[5]) + (red[6] + red[7]);
        out[(size_t)T_TOK * D_DIM + 0] = 1.25f * lsum / (float)((size_t)T_TOK * D_DIM);
        out[(size_t)T_TOK * D_DIM + 1] = expf(-ssum);
    }
}

extern "C" void kernel_launch(void* const* d_in, const int* in_sizes, int n_in,
                              void* d_out, int out_size, void* d_ws, size_t ws_size,
                              hipStream_t stream) {
    const float* z   = (const float*)d_in[0];   // [8,4096,128]
    const float* emb = (const float*)d_in[1];   // [8192,128]
    const float* pw  = (const float*)d_in[2];   // [128,128]
    const float* pb  = (const float*)d_in[3];   // [128]
    float* out = (float*)d_out;

    // Zpack (f16 split fragments, 16.78 MB) lives in d_out: dead scratch until
    // zq_kernel overwrites d_out with the final z_q_st.
    char* Zpack = (char*)d_out;

    char* ws = (char*)d_ws;
    // layout (bytes):
    //   Cpack:  0        .. 4194304   (128 cb x 32768)
    //   cn:     4194304  .. 4227072   (8192 f32)
    //   lpart:  4227072  .. 4243456   (4096 f32)
    //   packed: 4358144  .. 4620288   (32768 u64)
    //   counts: 4620288  .. 4653056   (8192 i32)
    char*  Cpack  = ws + 0;
    float* cn     = (float*)(ws + 4194304);
    float* lpart  = (float*)(ws + 4227072);
    ull*   packed = (ull*)  (ws + 4358144);
    int*   counts = (int*)  (ws + 4620288);

    proj_kernel<<<K_CODE / 4, 256, 0, stream>>>(emb, pw, pb, Cpack, cn);
    prep_z_kernel<<<T_TOK / 32, 256, 0, stream>>>(z, Zpack, packed, counts);
    argmin_kernel<<<(K_CODE / BN) * (T_TOK / BM), 256, 0, stream>>>(Zpack, Cpack, cn, packed);
    zq_kernel<<<(T_TOK * D_DIM / 4) / 256, 256, 0, stream>>>(z, Cpack, packed, out, counts, lpart);
    scalars_kernel<<<1, 256, 0, stream>>>(counts, lpart, out);
}

// Round 10
// 366.827 us; speedup vs baseline: 3.0974x; 1.0069x over previous
//
#include <hip/hip_runtime.h>
#include <math.h>

#define T_TOK 32768
#define D_DIM 128
#define K_CODE 8192
#define BM 256              // tokens per block (argmin): 4 waves x 64
#define BN 64               // codes per block (argmin)

typedef unsigned long long ull;
typedef _Float16 v8h __attribute__((ext_vector_type(8)));
typedef _Float16 v4h __attribute__((ext_vector_type(4)));
typedef float v16f __attribute__((ext_vector_type(16)));

#define SCALE 4096.0f        // 2^12: pushes f16 split residuals into normal range
#define DESCALE (1.0f / 4096.0f)
#define ACC_SCALE (-0x1p-23f)   // s' = cn - 2*dot (zn dropped: token-constant)

// Cpack layout (bytes): [cb=code/64][ (s*2+mt)*8+kc ][lane64][j8 f16]
// Zpack layout (bytes): [tb=token/32][ s ][ kc ][lane64][j8 f16]

// ---------------- prep: proj (blocks 0..2047) + prep_z (2048..3071) ---------
// Fused (R6's fused prep passed correctness; its regression was the zq
// done-counter's 4096 same-address atomics, NOT this): the two producers are
// independent, one dispatch runs them concurrently instead of serialized.
__global__ __launch_bounds__(256) void prep_kernel(const float* __restrict__ E,
                                                   const float* __restrict__ W,
                                                   const float* __restrict__ b,
                                                   char* __restrict__ Cpack,
                                                   float* __restrict__ cn,
                                                   const float* __restrict__ Z,
                                                   char* __restrict__ Zpack,
                                                   ull* __restrict__ packed,
                                                   int* __restrict__ counts) {
    int tid = threadIdx.x;
    int lane = tid & 63;
    if (blockIdx.x < 2048) {
        // ---- proj: codebook row -> f16 split packs + cn (1 wave / row) ----
        int r = blockIdx.x * 4 + (tid >> 6);
        int l = lane;
        const float4* E4 = (const float4*)(E + (size_t)r * D_DIM);
        const float4* WA = (const float4*)(W + (size_t)l * D_DIM);
        const float4* WB = (const float4*)(W + (size_t)(l + 64) * D_DIM);

        float4 aA = make_float4(0.f, 0.f, 0.f, 0.f);
        float4 aB = make_float4(0.f, 0.f, 0.f, 0.f);
#pragma unroll
        for (int dd = 0; dd < 32; ++dd) {
            float4 e = E4[dd];
            float4 wa = WA[dd], wb = WB[dd];
            aA.x = fmaf(e.x, wa.x, aA.x);
            aA.y = fmaf(e.y, wa.y, aA.y);
            aA.z = fmaf(e.z, wa.z, aA.z);
            aA.w = fmaf(e.w, wa.w, aA.w);
            aB.x = fmaf(e.x, wb.x, aB.x);
            aB.y = fmaf(e.y, wb.y, aB.y);
            aB.z = fmaf(e.z, wb.z, aB.z);
            aB.w = fmaf(e.w, wb.w, aB.w);
        }
        float vA = ((aA.x + aA.y) + (aA.z + aA.w)) + b[l];
        float vB = ((aB.x + aB.y) + (aB.z + aB.w)) + b[l + 64];

        char* cp = Cpack + (size_t)(r >> 6) * 32768;
        int mt = (r >> 5) & 1, rs = r & 31;
        {   // d = l
            int kc = l >> 4, hf = (l >> 3) & 1, j = l & 7;
            float f = vA * SCALE;
            _Float16 h = (_Float16)f;
            _Float16 m = (_Float16)(f - (float)h);
            size_t off = (size_t)((mt * 8 + kc) * 1024 + (hf * 32 + rs) * 16 + j * 2);
            *(_Float16*)(cp + off) = h;
            *(_Float16*)(cp + off + 16384) = m;
        }
        {   // d = l + 64
            int d = l + 64;
            int kc = d >> 4, hf = (d >> 3) & 1, j = d & 7;
            float f = vB * SCALE;
            _Float16 h = (_Float16)f;
            _Float16 m = (_Float16)(f - (float)h);
            size_t off = (size_t)((mt * 8 + kc) * 1024 + (hf * 32 + rs) * 16 + j * 2);
            *(_Float16*)(cp + off) = h;
            *(_Float16*)(cp + off + 16384) = m;
        }

        float s = vA * vA + vB * vB;
#pragma unroll
        for (int off = 32; off > 0; off >>= 1) s += __shfl_down(s, off, 64);
        if (l == 0) cn[r] = s;
    } else {
        // ---- prep_z: z -> f16 split packs + fused inits ----
        int tb = blockIdx.x - 2048;   // 32-token group
        int w = tid >> 6;

        int g = tb * 256 + tid;
        if (g < T_TOK) packed[g] = ~0ull;
        if (g < K_CODE) counts[g] = 0;

        char* zp = Zpack + (size_t)tb * 16384;
#pragma unroll
        for (int kq = 0; kq < 2; ++kq) {
            int kc = 2 * w + kq;
            const float* src = Z + (size_t)(tb * 32 + (lane & 31)) * D_DIM
                                 + kc * 16 + (lane >> 5) * 8;
            float4 a = *(const float4*)(src);
            float4 c = *(const float4*)(src + 4);
            float vals[8] = {a.x, a.y, a.z, a.w, c.x, c.y, c.z, c.w};
            v8h h, m;
#pragma unroll
            for (int j = 0; j < 8; ++j) {
                float f = vals[j] * SCALE;
                _Float16 hh = (_Float16)f;
                h[j] = hh;
                m[j] = (_Float16)(f - (float)hh);
            }
            *(v8h*)(zp + (size_t)(kc * 1024 + lane * 16)) = h;
            *(v8h*)(zp + (size_t)(8192 + kc * 1024 + lane * 16)) = m;
        }
    }
}

// ---------------- MFMA argmin: explicit A double-buffer (LDS->MFMA hoist) ---
// R18 post-mortem chain: five schedules (R0/R4/R5/R7/R8: occupancy 8->16
// waves/CU, B-prefetch depth 2->3, block 256->512) ALL pin at 206-208us /
// 47-51% MfmaUtil. Matrix pipe when busy runs at ~95% of the f16 floor
// (99us busy vs 94.6us floor) -> the wall is pure idle. R8 falsified B-refill
// latency (2600-cyc distance, no change). Last unprobed dependency: the A
// ds_reads are consumed by the IMMEDIATELY following MFMA cluster (~150cyc
// lgkmcnt exposed per cluster), and R5's launch_bounds(256,4) left the
// compiler no register headroom to hoist. R9: explicit A double-buffer --
// body issues kc+1's four ds_read_b128 into the alternate set BEFORE the
// MFMAs of kc -> ds_read->use distance = 12 MFMA (~400+ cyc). +32 VGPR at
// (256,3): ~159 unified < 170 budget. pb 3-slot, swizzle, epilogue, atomics
// R8-exact.
__global__ __launch_bounds__(256, 3) void argmin_kernel(const char* __restrict__ Zpack,
                                                        const char* __restrict__ Cpack,
                                                        const float* __restrict__ cn,
                                                        ull* __restrict__ packed) {
    __shared__ __align__(16) char lds[33024];   // 32768 A-pack + 256 cn

    int tid = threadIdx.x;
    int lane = tid & 63;
    int w = tid >> 6;                  // 0..3
    int half_id = lane >> 5;

    // XCD swizzle (R5-identical): window in HIGH bits of q -> co-resident
    // blocks share one window (L2-hot Zpack); Cpack cycles L2-resident.
    int bid = blockIdx.x;
    int xcd = bid & 7;
    int q = bid >> 3;
    int cb = q & 127;                  // code block (64 codes)
    int win = xcd + 8 * (q >> 7);      // token window (256 tokens)
    int nb = cb * BN;
    int mb = win * BM;

    // ---- one-time stage: A-pack via async global_load_lds (16B, linear) ----
    {
        const char* src = Cpack + (size_t)cb * 32768;
#pragma unroll
        for (int it = 0; it < 8; ++it) {
            int off = it * 4096 + tid * 16;
            __builtin_amdgcn_global_load_lds(
                (const __attribute__((address_space(1))) void*)(src + off),
                (__attribute__((address_space(3))) void*)(lds + off),
                16, 0, 0);
        }
        if (tid < 64) ((float*)(lds + 32768))[tid] = cn[nb + tid];
    }

    int tbw = (mb >> 5) + 2 * w;       // wave w owns token groups 2w, 2w+1
    const char* zb0 = Zpack + (size_t)tbw * 16384 + lane * 16;

    // 3-slot register prefetch: pb[frag = n*2 + split][slot = kc%3]
    v8h pb[4][3];
#pragma unroll
    for (int n = 0; n < 2; ++n) {
        pb[2 * n + 0][0] = *(const v8h*)(zb0 + n * 16384);
        pb[2 * n + 1][0] = *(const v8h*)(zb0 + n * 16384 + 8192);
        pb[2 * n + 0][1] = *(const v8h*)(zb0 + n * 16384 + 1024);
        pb[2 * n + 1][1] = *(const v8h*)(zb0 + n * 16384 + 8192 + 1024);
    }

    __syncthreads();   // drains staging; LDS read-only after this

    const char* ab = lds + lane * 16;
    const float* cn_s = (const float*)(lds + 32768);

    v16f acc[2][2];               // [mt codes][n token-groups]
#pragma unroll
    for (int mt = 0; mt < 2; ++mt)
#pragma unroll
        for (int n = 0; n < 2; ++n) acc[mt][n] = (v16f)0.f;

    // A double-buffer: Af[kc&1][frag] -- prologue loads kc=0 (post-barrier)
    v8h Af[2][4];
#pragma unroll
    for (int f = 0; f < 4; ++f)
        Af[0][f] = *(const v8h*)(ab + (f * 8 + 0) * 1024);

#pragma unroll
    for (int kc = 0; kc < 8; ++kc) {
        int curb = kc % 3;
        int cura = kc & 1;

        // issue kc+1's A ds_reads FIRST (consumed after 12 MFMAs ~400+ cyc)
        if (kc < 7) {
#pragma unroll
            for (int f = 0; f < 4; ++f)
                Af[cura ^ 1][f] = *(const v8h*)(ab + (f * 8 + kc + 1) * 1024);
        }

        // deep B refill: slot (kc+2)%3 was consumed at kc-1; its new data is
        // consumed at kc+2 -> 2 full bodies of latency headroom.
        if (kc < 6) {
            int slot = (kc + 2) % 3;
#pragma unroll
            for (int n = 0; n < 2; ++n) {
                pb[2 * n + 0][slot] = *(const v8h*)(zb0 + n * 16384 + (kc + 2) * 1024);
                pb[2 * n + 1][slot] = *(const v8h*)(zb0 + n * 16384 + 8192 + (kc + 2) * 1024);
            }
        }

        __builtin_amdgcn_s_setprio(1);
        // pass h*h  (A frags resident since previous body)
#pragma unroll
        for (int n = 0; n < 2; ++n)
            acc[0][n] = __builtin_amdgcn_mfma_f32_32x32x16_f16(Af[cura][0], pb[2 * n][curb], acc[0][n], 0, 0, 0);
#pragma unroll
        for (int n = 0; n < 2; ++n)
            acc[1][n] = __builtin_amdgcn_mfma_f32_32x32x16_f16(Af[cura][1], pb[2 * n][curb], acc[1][n], 0, 0, 0);
        // pass h*m
#pragma unroll
        for (int n = 0; n < 2; ++n)
            acc[0][n] = __builtin_amdgcn_mfma_f32_32x32x16_f16(Af[cura][0], pb[2 * n + 1][curb], acc[0][n], 0, 0, 0);
#pragma unroll
        for (int n = 0; n < 2; ++n)
            acc[1][n] = __builtin_amdgcn_mfma_f32_32x32x16_f16(Af[cura][1], pb[2 * n + 1][curb], acc[1][n], 0, 0, 0);
        // pass m*h
#pragma unroll
        for (int n = 0; n < 2; ++n)
            acc[0][n] = __builtin_amdgcn_mfma_f32_32x32x16_f16(Af[cura][2], pb[2 * n][curb], acc[0][n], 0, 0, 0);
#pragma unroll
        for (int n = 0; n < 2; ++n)
            acc[1][n] = __builtin_amdgcn_mfma_f32_32x32x16_f16(Af[cura][3], pb[2 * n][curb], acc[1][n], 0, 0, 0);
        __builtin_amdgcn_s_setprio(0);
    }

    // ---- epilogue: in-lane argmin per token group (zn-free: s' = cn - 2dot,
    // token-constant zn cancels in every comparison) ----
    float best[2];
    int bi[2];
#pragma unroll
    for (int n = 0; n < 2; ++n) { best[n] = 3.4e38f; bi[n] = nb; }

#pragma unroll
    for (int mt = 0; mt < 2; ++mt) {
        float cnreg[16];
#pragma unroll
        for (int reg = 0; reg < 16; ++reg) {
            int mrow = 32 * mt + (reg & 3) + 8 * (reg >> 2) + 4 * half_id;
            cnreg[reg] = cn_s[mrow];
        }
#pragma unroll
        for (int n = 0; n < 2; ++n) {
#pragma unroll
            for (int reg = 0; reg < 16; ++reg) {
                // ascending code order within half -> strict < keeps first-min
                int mrow = 32 * mt + (reg & 3) + 8 * (reg >> 2) + 4 * half_id;
                int code = nb + mrow;
                float s = fmaf(acc[mt][n][reg], ACC_SCALE, cnreg[reg]);
                if (s < best[n]) { best[n] = s; bi[n] = code; }
            }
        }
    }

    // cross-half combine + XCD-local packed atomicMin
#pragma unroll
    for (int n = 0; n < 2; ++n) {
        float ob = __shfl_xor(best[n], 32, 64);
        int oi = __shfl_xor(bi[n], 32, 64);
        if (ob < best[n] || (ob == best[n] && oi < bi[n])) { best[n] = ob; bi[n] = oi; }
        if ((n & 1) == half_id) {
            int tok = mb + w * 64 + n * 32 + (lane & 31);
            // monotone total-order encode of f32 (s' may be negative):
            // >=0: u^0x80000000 ; <0: u^0xFFFFFFFF. Equal s' -> equal key ->
            // min picks smaller code in low bits (first-min ties preserved).
            unsigned ub = __float_as_uint(best[n]);
            unsigned key = ub ^ ((unsigned)(((int)ub) >> 31) | 0x80000000u);
            ull pk = ((ull)key << 32) | (unsigned)bi[n];
            atomicMin(&packed[tok], pk);
        }
    }
}

// ---------------- zq: unpack winner, reconstruct code row, out + counts + loss
__global__ __launch_bounds__(256) void zq_kernel(const float* __restrict__ Z,
                                                 const char* __restrict__ Cpack,
                                                 const ull* __restrict__ packed,
                                                 float* __restrict__ out,
                                                 int* __restrict__ counts,
                                                 float* __restrict__ lpart) {
    int gid = blockIdx.x * 256 + threadIdx.x;   // over T*D/4 float4s
    int t = gid >> 5;                           // 32 float4 per token
    int d4 = gid & 31;
    int idx = (int)(packed[t] & 0xFFFFFFFFull);
    if (d4 == 0) atomicAdd(&counts[idx], 1);

    // reconstruct c[d0..d0+3] = (ch + cm) * 2^-12 (exact sum: spans < 24 bits)
    int d0 = 4 * d4;
    int kc = d0 >> 4, hf = (d0 >> 3) & 1, j0 = d0 & 7;
    const char* cp = Cpack + (size_t)(idx >> 6) * 32768
                   + (size_t)((((idx >> 5) & 1) * 8 + kc) * 1024
                              + (hf * 32 + (idx & 31)) * 16 + j0 * 2);
    v4h h = *(const v4h*)(cp);
    v4h m = *(const v4h*)(cp + 16384);
    float4 cv;
    cv.x = ((float)h[0] + (float)m[0]) * DESCALE;
    cv.y = ((float)h[1] + (float)m[1]) * DESCALE;
    cv.z = ((float)h[2] + (float)m[2]) * DESCALE;
    cv.w = ((float)h[3] + (float)m[3]) * DESCALE;

    float4 zv = ((const float4*)Z)[gid];
    float dx = cv.x - zv.x, dy = cv.y - zv.y, dz = cv.z - zv.z, dw = cv.w - zv.w;
    float4 o;
    o.x = zv.x + dx;    // z + (z_q - z): match reference elementwise rounding
    o.y = zv.y + dy;
    o.z = zv.z + dz;
    o.w = zv.w + dw;
    ((float4*)out)[gid] = o;

    float ls = dx * dx + dy * dy + dz * dz + dw * dw;
#pragma unroll
    for (int off = 32; off > 0; off >>= 1) ls += __shfl_down(ls, off, 64);
    __shared__ float red[4];
    int lane = threadIdx.x & 63, w = threadIdx.x >> 6;
    if (lane == 0) red[w] = ls;
    __syncthreads();
    // per-block partial store: no same-address atomic serialization
    if (threadIdx.x == 0) lpart[blockIdx.x] = (red[0] + red[1]) + (red[2] + red[3]);
}

// ---------------- scalars: commit_loss (from partials), perplexity ----------
__global__ __launch_bounds__(256) void scalars_kernel(const int* __restrict__ counts,
                                                      const float* __restrict__ lpart,
                                                      float* __restrict__ out) {
    float s = 0.f;
    for (int i = threadIdx.x; i < K_CODE; i += 256) {
        float e = (float)counts[i] * (1.0f / (float)T_TOK);
        s += e * logf(e + 1e-8f);
    }
    float ls = 0.f;
    for (int i = threadIdx.x; i < 4096; i += 256) ls += lpart[i];
#pragma unroll
    for (int off = 32; off > 0; off >>= 1) {
        s += __shfl_down(s, off, 64);
        ls += __shfl_down(ls, off, 64);
    }
    __shared__ float red[8];
    int lane = threadIdx.x & 63, w = threadIdx.x >> 6;
    if (lane == 0) { red[w] = s; red[4 + w] = ls; }
    __syncthreads();
    if (threadIdx.x == 0) {
        float ssum = (red[0] + red[1]) + (red[2] + red[3]);
        float lsum = (red[4] + red[5]) + (red[6] + red[7]);
        out[(size_t)T_TOK * D_DIM + 0] = 1.25f * lsum / (float)((size_t)T_TOK * D_DIM);
        out[(size_t)T_TOK * D_DIM + 1] = expf(-ssum);
    }
}

extern "C" void kernel_launch(void* const* d_in, const int* in_sizes, int n_in,
                              void* d_out, int out_size, void* d_ws, size_t ws_size,
                              hipStream_t stream) {
    const float* z   = (const float*)d_in[0];   // [8,4096,128]
    const float* emb = (const float*)d_in[1];   // [8192,128]
    const float* pw  = (const float*)d_in[2];   // [128,128]
    const float* pb  = (const float*)d_in[3];   // [128]
    float* out = (float*)d_out;

    // Zpack (f16 split fragments, 16.78 MB) lives in d_out: dead scratch until
    // zq_kernel overwrites d_out with the final z_q_st.
    char* Zpack = (char*)d_out;

    char* ws = (char*)d_ws;
    // layout (bytes):
    //   Cpack:  0        .. 4194304   (128 cb x 32768)
    //   cn:     4194304  .. 4227072   (8192 f32)
    //   lpart:  4227072  .. 4243456   (4096 f32)
    //   packed: 4358144  .. 4620288   (32768 u64)
    //   counts: 4620288  .. 4653056   (8192 i32)
    char*  Cpack  = ws + 0;
    float* cn     = (float*)(ws + 4194304);
    float* lpart  = (float*)(ws + 4227072);
    ull*   packed = (ull*)  (ws + 4358144);
    int*   counts = (int*)  (ws + 4620288);

    prep_kernel<<<3072, 256, 0, stream>>>(emb, pw, pb, Cpack, cn, z, Zpack, packed, counts);
    argmin_kernel<<<(K_CODE / BN) * (T_TOK / BM), 256, 0, stream>>>(Zpack, Cpack, cn, packed);
    zq_kernel<<<(T_TOK * D_DIM / 4) / 256, 256, 0, stream>>>(z, Cpack, packed, out, counts, lpart);
    scalars_kernel<<<1, 256, 0, stream>>>(counts, lpart, out);
}